// Round 3
// baseline (296.295 us; speedup 1.0000x reference)
//
#include <hip/hip_runtime.h>
#include <hip/hip_cooperative_groups.h>

namespace cg = cooperative_groups;

// ---------------- problem constants (fixed by setup_inputs) ----------------
constexpr int Bn = 16, An = 3, Cn = 80;
constexpr int N_LL = 4000, N_ML = 2000, N_HL = 800;
constexpr int G_LL = 80,  G_ML = 40,   G_HL = 20;
constexpr int CELLS_LL = Bn * An * G_LL * G_LL;   // 307200
constexpr int CELLS_ML = Bn * An * G_ML * G_ML;   //  76800
constexpr int CELLS_HL = Bn * An * G_HL * G_HL;   //  19200

// vec4 work-item counts
constexpr int OBJ4_LL = CELLS_LL / 4;             // 76800
constexpr int OBJ4_ML = CELLS_ML / 4;             // 19200
constexpr int OBJ4_HL = CELLS_HL / 4;             //  4800
constexpr int OBJ4    = OBJ4_LL + OBJ4_ML + OBJ4_HL;   // 100800
constexpr int ROW4    = Cn / 4;                   // 20 float4 per cls row
constexpr int CLS4_LL = N_LL * ROW4;              // 80000
constexpr int CLS4_ML = N_ML * ROW4;              // 40000
constexpr int CLS4_HL = N_HL * ROW4;              // 16000
constexpr int CLS4    = CLS4_LL + CLS4_ML + CLS4_HL;   // 136000
constexpr int NBOX    = N_LL + N_ML + N_HL;       // 6800
constexpr int TOTAL   = OBJ4 + CLS4 + NBOX;       // 243600

constexpr int TB   = 256;
constexpr int GRID = (TOTAL + TB - 1) / TB;       // 952  (952*4=3808 waves << 8192 capacity)

// weights
constexpr float L_CLS = 0.5f, L_LOC = 0.05f, L_OBJ = 1.0f;
constexpr float R_LL = 4.0f, R_ML = 1.0f, R_HL = 0.4f;
constexpr float LAM_CLS = L_CLS * ((float)Cn / 80.0f);   // 0.5

__device__ __forceinline__ float softplus0(float x) {
    // bce(x, 0) = max(x,0) + log1p(exp(-|x|))
    return fmaxf(x, 0.0f) + log1pf(expf(-fabsf(x)));
}

__device__ __forceinline__ float bce_logits(float x, float z) {
    return fmaxf(x, 0.0f) - x * z + log1pf(expf(-fabsf(x)));
}

__device__ __forceinline__ float sigmoidf(float x) {
    return 1.0f / (1.0f + expf(-x));
}

struct Scale {
    const float* box; const float* obj; const float* cls;
    const int* smp; const int* anc; const int* gy; const int* gx;
    const float* awh; const float* gt; const int* lab;
    int G;
};

// ---------------- single fused cooperative kernel ----------------
// ws layout: ws[k*GRID + b], k = 0(loc) 1(obj, pre-lambda) 2(cls)
__global__ __launch_bounds__(TB, 4)
void k_all(Scale ll, Scale ml, Scale hl,
           float* __restrict__ ws,
           const int* __restrict__ imgw_p,
           float* __restrict__ out) {
    const int i = blockIdx.x * TB + threadIdx.x;
    float loc_s = 0.0f, obj_s = 0.0f, cls_s = 0.0f;

    if (i < OBJ4) {
        // ---- objectness softplus stream (vec4, coalesced) ----
        const float4* p; float w;
        if (i < OBJ4_LL)                    { p = (const float4*)ll.obj + i;                       w = R_LL / (float)CELLS_LL; }
        else if (i < OBJ4_LL + OBJ4_ML)     { p = (const float4*)ml.obj + (i - OBJ4_LL);           w = R_ML / (float)CELLS_ML; }
        else                                { p = (const float4*)hl.obj + (i - OBJ4_LL - OBJ4_ML); w = R_HL / (float)CELLS_HL; }
        const float4 x = *p;
        obj_s = w * (softplus0(x.x) + softplus0(x.y) + softplus0(x.z) + softplus0(x.w));
    } else if (i < OBJ4 + CLS4) {
        // ---- classification BCE over gathered rows (vec4; 20 consecutive lanes share a row) ----
        const int j = i - OBJ4;
        Scale s; int local; float w;
        if (j < CLS4_LL)                 { s = ll; local = j;                     w = LAM_CLS / (float)(N_LL * Cn); }
        else if (j < CLS4_LL + CLS4_ML)  { s = ml; local = j - CLS4_LL;           w = LAM_CLS / (float)(N_ML * Cn); }
        else                             { s = hl; local = j - CLS4_LL - CLS4_ML; w = LAM_CLS / (float)(N_HL * Cn); }
        const int n = local / ROW4, q = local - n * ROW4;
        const int cell = ((s.smp[n] * An + s.anc[n]) * s.G + s.gy[n]) * s.G + s.gx[n];
        const float4 x = reinterpret_cast<const float4*>(s.cls)[cell * ROW4 + q];
        const int lab = s.lab[n], c0 = q * 4;
        cls_s = w * (bce_logits(x.x, (lab == c0    ) ? 1.0f : 0.0f) +
                     bce_logits(x.y, (lab == c0 + 1) ? 1.0f : 0.0f) +
                     bce_logits(x.z, (lab == c0 + 2) ? 1.0f : 0.0f) +
                     bce_logits(x.w, (lab == c0 + 3) ? 1.0f : 0.0f));
    } else if (i < TOTAL) {
        // ---- box: iou -> loc loss + obj correction term (bce(x,t)-bce(x,0) = -x*t) ----
        const int j = i - OBJ4 - CLS4;
        Scale s; int n; float locW, objW;
        if (j < N_LL)              { s = ll; n = j;               locW = L_LOC / (float)N_LL; objW = R_LL / (float)CELLS_LL; }
        else if (j < N_LL + N_ML)  { s = ml; n = j - N_LL;        locW = L_LOC / (float)N_ML; objW = R_ML / (float)CELLS_ML; }
        else                       { s = hl; n = j - N_LL - N_ML; locW = L_LOC / (float)N_HL; objW = R_HL / (float)CELLS_HL; }
        const int cell = ((s.smp[n] * An + s.anc[n]) * s.G + s.gy[n]) * s.G + s.gx[n];
        const float4 fp = reinterpret_cast<const float4*>(s.box)[cell];
        const float sx = sigmoidf(fp.x), sy = sigmoidf(fp.y);
        const float sw = sigmoidf(fp.z), sh = sigmoidf(fp.w);
        const float px = sx * 2.0f - 0.5f;
        const float py = sy * 2.0f - 0.5f;
        const float aw = s.awh[2 * n], ah = s.awh[2 * n + 1];
        const float pw = (sw * 2.0f) * (sw * 2.0f) * aw;
        const float ph = (sh * 2.0f) * (sh * 2.0f) * ah;
        const float ax1 = px - pw * 0.5f, ay1 = py - ph * 0.5f;
        const float ax2 = px + pw * 0.5f, ay2 = py + ph * 0.5f;
        const float4 g = reinterpret_cast<const float4*>(s.gt)[n];
        const float bx1 = g.x - g.z * 0.5f, by1 = g.y - g.w * 0.5f;
        const float bx2 = g.x + g.z * 0.5f, by2 = g.y + g.w * 0.5f;
        const float lx = fmaxf(ax1, bx1), ly = fmaxf(ay1, by1);
        const float rx = fminf(ax2, bx2), ry = fminf(ay2, by2);
        const float iw = fmaxf(rx - lx, 0.0f), ih = fmaxf(ry - ly, 0.0f);
        const float inter = iw * ih;
        const float iou = inter / (pw * ph + g.z * g.w - inter + 1e-7f);
        loc_s = locW * (1.0f - iou);
        obj_s = -objW * s.obj[cell] * iou;
    }

    // ---- phase 1 epilogue: block-reduce 3 sums -> ws ----
    {
        float v[3] = {loc_s, obj_s, cls_s};
        __shared__ float sm[3][4];
        const int lane = threadIdx.x & 63, wid = threadIdx.x >> 6;
        #pragma unroll
        for (int k = 0; k < 3; ++k) {
            float t = v[k];
            for (int o = 32; o > 0; o >>= 1) t += __shfl_down(t, o, 64);
            if (lane == 0) sm[k][wid] = t;
        }
        __syncthreads();
        if (threadIdx.x == 0) {
            #pragma unroll
            for (int k = 0; k < 3; ++k)
                ws[k * GRID + blockIdx.x] = sm[k][0] + sm[k][1] + sm[k][2] + sm[k][3];
        }
    }

    // ---- grid barrier, then block 0 finalizes ----
    cg::this_grid().sync();
    if (blockIdx.x != 0) return;

    float v0 = 0.0f, v1 = 0.0f, v2 = 0.0f;
    for (int b = threadIdx.x; b < GRID; b += TB) {
        v0 += ws[0 * GRID + b];
        v1 += ws[1 * GRID + b];
        v2 += ws[2 * GRID + b];
    }
    for (int o = 32; o > 0; o >>= 1) {
        v0 += __shfl_down(v0, o, 64);
        v1 += __shfl_down(v1, o, 64);
        v2 += __shfl_down(v2, o, 64);
    }
    __shared__ float fm[3][4];
    const int lane = threadIdx.x & 63, wid = threadIdx.x >> 6;
    if (lane == 0) { fm[0][wid] = v0; fm[1][wid] = v1; fm[2][wid] = v2; }
    __syncthreads();
    if (threadIdx.x == 0) {
        const float s = (float)(*imgw_p) / 640.0f;
        out[0] = fm[0][0] + fm[0][1] + fm[0][2] + fm[0][3];
        out[1] = (fm[1][0] + fm[1][1] + fm[1][2] + fm[1][3]) * (L_OBJ * s * s);
        out[2] = fm[2][0] + fm[2][1] + fm[2][2] + fm[2][3];
    }
}

// ---------------- launch ----------------
extern "C" void kernel_launch(void* const* d_in, const int* in_sizes, int n_in,
                              void* d_out, int out_size, void* d_ws, size_t ws_size,
                              hipStream_t stream) {
    Scale ll{(const float*)d_in[0],  (const float*)d_in[1],  (const float*)d_in[2],
             (const int*)d_in[3],    (const int*)d_in[4],    (const int*)d_in[5],
             (const int*)d_in[6],    (const float*)d_in[7],  (const float*)d_in[8],
             (const int*)d_in[9],    G_LL};
    Scale ml{(const float*)d_in[10], (const float*)d_in[11], (const float*)d_in[12],
             (const int*)d_in[13],   (const int*)d_in[14],   (const int*)d_in[15],
             (const int*)d_in[16],   (const float*)d_in[17], (const float*)d_in[18],
             (const int*)d_in[19],   G_ML};
    Scale hl{(const float*)d_in[20], (const float*)d_in[21], (const float*)d_in[22],
             (const int*)d_in[23],   (const int*)d_in[24],   (const int*)d_in[25],
             (const int*)d_in[26],   (const float*)d_in[27], (const float*)d_in[28],
             (const int*)d_in[29],   G_HL};
    const int* imgw = (const int*)d_in[30];

    float* out = (float*)d_out;
    float* ws  = (float*)d_ws;   // 3*GRID floats = 11.2 KB, all written before read

    void* args[] = {&ll, &ml, &hl, &ws, &imgw, &out};
    hipLaunchCooperativeKernel((void*)k_all, dim3(GRID), dim3(TB), args, 0, stream);
}

// Round 4
// 203.494 us; speedup vs baseline: 1.4560x; 1.4560x over previous
//
#include <hip/hip_runtime.h>

// ---------------- problem constants (fixed by setup_inputs) ----------------
constexpr int Bn = 16, An = 3, Cn = 80;
constexpr int N_LL = 4000, N_ML = 2000, N_HL = 800;
constexpr int G_LL = 80,  G_ML = 40,   G_HL = 20;
constexpr int CELLS_LL = Bn * An * G_LL * G_LL;   // 307200
constexpr int CELLS_ML = Bn * An * G_ML * G_ML;   //  76800
constexpr int CELLS_HL = Bn * An * G_HL * G_HL;   //  19200

// vec4 work-item counts
constexpr int OBJ4_LL = CELLS_LL / 4;             // 76800
constexpr int OBJ4_ML = CELLS_ML / 4;             // 19200
constexpr int OBJ4_HL = CELLS_HL / 4;             //  4800
constexpr int OBJ4    = OBJ4_LL + OBJ4_ML + OBJ4_HL;   // 100800
constexpr int ROW4    = Cn / 4;                   // 20 float4 per cls row
constexpr int CLS4_LL = N_LL * ROW4;              // 80000
constexpr int CLS4_ML = N_ML * ROW4;              // 40000
constexpr int CLS4_HL = N_HL * ROW4;              // 16000
constexpr int CLS4    = CLS4_LL + CLS4_ML + CLS4_HL;   // 136000
constexpr int NBOX    = N_LL + N_ML + N_HL;       // 6800
constexpr int TOTAL   = OBJ4 + CLS4 + NBOX;       // 243600

constexpr int TB   = 256;
constexpr int GRID = (TOTAL + TB - 1) / TB;       // 952

// weights
constexpr float L_CLS = 0.5f, L_LOC = 0.05f, L_OBJ = 1.0f;
constexpr float R_LL = 4.0f, R_ML = 1.0f, R_HL = 0.4f;
constexpr float LAM_CLS = L_CLS * ((float)Cn / 80.0f);   // 0.5

__device__ __forceinline__ float softplus0(float x) {
    // bce(x, 0) = max(x,0) + log1p(exp(-|x|))
    return fmaxf(x, 0.0f) + log1pf(expf(-fabsf(x)));
}

__device__ __forceinline__ float bce_logits(float x, float z) {
    return fmaxf(x, 0.0f) - x * z + log1pf(expf(-fabsf(x)));
}

__device__ __forceinline__ float sigmoidf(float x) {
    return 1.0f / (1.0f + expf(-x));
}

struct Scale {
    const float* box; const float* obj; const float* cls;
    const int* smp; const int* anc; const int* gy; const int* gx;
    const float* awh; const float* gt; const int* lab;
    int G;
};

// ---------------- K1: fused main kernel ----------------
// ws layout: ws[k*GRID + blockIdx.x], k = 0(loc) 1(obj, pre-lambda) 2(cls)
__global__ __launch_bounds__(TB) void k_main(Scale ll, Scale ml, Scale hl,
                                             float* __restrict__ ws) {
    const int i = blockIdx.x * TB + threadIdx.x;
    float loc_s = 0.0f, obj_s = 0.0f, cls_s = 0.0f;

    if (i < OBJ4) {
        // ---- objectness softplus stream (vec4, coalesced) ----
        const float4* p; float w;
        if (i < OBJ4_LL)                    { p = (const float4*)ll.obj + i;                       w = R_LL / (float)CELLS_LL; }
        else if (i < OBJ4_LL + OBJ4_ML)     { p = (const float4*)ml.obj + (i - OBJ4_LL);           w = R_ML / (float)CELLS_ML; }
        else                                { p = (const float4*)hl.obj + (i - OBJ4_LL - OBJ4_ML); w = R_HL / (float)CELLS_HL; }
        const float4 x = *p;
        obj_s = w * (softplus0(x.x) + softplus0(x.y) + softplus0(x.z) + softplus0(x.w));
    } else if (i < OBJ4 + CLS4) {
        // ---- classification BCE over gathered rows (vec4; 20 consecutive lanes share a row) ----
        const int j = i - OBJ4;
        Scale s; int local; float w;
        if (j < CLS4_LL)                 { s = ll; local = j;                     w = LAM_CLS / (float)(N_LL * Cn); }
        else if (j < CLS4_LL + CLS4_ML)  { s = ml; local = j - CLS4_LL;           w = LAM_CLS / (float)(N_ML * Cn); }
        else                             { s = hl; local = j - CLS4_LL - CLS4_ML; w = LAM_CLS / (float)(N_HL * Cn); }
        const int n = local / ROW4, q = local - n * ROW4;
        const int cell = ((s.smp[n] * An + s.anc[n]) * s.G + s.gy[n]) * s.G + s.gx[n];
        const float4 x = reinterpret_cast<const float4*>(s.cls)[cell * ROW4 + q];
        const int lab = s.lab[n], c0 = q * 4;
        cls_s = w * (bce_logits(x.x, (lab == c0    ) ? 1.0f : 0.0f) +
                     bce_logits(x.y, (lab == c0 + 1) ? 1.0f : 0.0f) +
                     bce_logits(x.z, (lab == c0 + 2) ? 1.0f : 0.0f) +
                     bce_logits(x.w, (lab == c0 + 3) ? 1.0f : 0.0f));
    } else if (i < TOTAL) {
        // ---- box: iou -> loc loss + obj correction term (bce(x,t)-bce(x,0) = -x*t) ----
        const int j = i - OBJ4 - CLS4;
        Scale s; int n; float locW, objW;
        if (j < N_LL)              { s = ll; n = j;               locW = L_LOC / (float)N_LL; objW = R_LL / (float)CELLS_LL; }
        else if (j < N_LL + N_ML)  { s = ml; n = j - N_LL;        locW = L_LOC / (float)N_ML; objW = R_ML / (float)CELLS_ML; }
        else                       { s = hl; n = j - N_LL - N_ML; locW = L_LOC / (float)N_HL; objW = R_HL / (float)CELLS_HL; }
        const int cell = ((s.smp[n] * An + s.anc[n]) * s.G + s.gy[n]) * s.G + s.gx[n];
        const float4 fp = reinterpret_cast<const float4*>(s.box)[cell];
        const float sx = sigmoidf(fp.x), sy = sigmoidf(fp.y);
        const float sw = sigmoidf(fp.z), sh = sigmoidf(fp.w);
        const float px = sx * 2.0f - 0.5f;
        const float py = sy * 2.0f - 0.5f;
        const float aw = s.awh[2 * n], ah = s.awh[2 * n + 1];
        const float pw = (sw * 2.0f) * (sw * 2.0f) * aw;
        const float ph = (sh * 2.0f) * (sh * 2.0f) * ah;
        const float ax1 = px - pw * 0.5f, ay1 = py - ph * 0.5f;
        const float ax2 = px + pw * 0.5f, ay2 = py + ph * 0.5f;
        const float4 g = reinterpret_cast<const float4*>(s.gt)[n];
        const float bx1 = g.x - g.z * 0.5f, by1 = g.y - g.w * 0.5f;
        const float bx2 = g.x + g.z * 0.5f, by2 = g.y + g.w * 0.5f;
        const float lx = fmaxf(ax1, bx1), ly = fmaxf(ay1, by1);
        const float rx = fminf(ax2, bx2), ry = fminf(ay2, by2);
        const float iw = fmaxf(rx - lx, 0.0f), ih = fmaxf(ry - ly, 0.0f);
        const float inter = iw * ih;
        const float iou = inter / (pw * ph + g.z * g.w - inter + 1e-7f);
        loc_s = locW * (1.0f - iou);
        obj_s = -objW * s.obj[cell] * iou;
    }

    // ---- block reduce all three sums, one __syncthreads ----
    float v[3] = {loc_s, obj_s, cls_s};
    __shared__ float sm[3][4];
    const int lane = threadIdx.x & 63, wid = threadIdx.x >> 6;
    #pragma unroll
    for (int k = 0; k < 3; ++k) {
        float t = v[k];
        for (int o = 32; o > 0; o >>= 1) t += __shfl_down(t, o, 64);
        if (lane == 0) sm[k][wid] = t;
    }
    __syncthreads();
    if (threadIdx.x == 0) {
        #pragma unroll
        for (int k = 0; k < 3; ++k)
            ws[k * GRID + blockIdx.x] = sm[k][0] + sm[k][1] + sm[k][2] + sm[k][3];
    }
}

// ---------------- K2: finalize (single block, no atomics) ----------------
__global__ __launch_bounds__(TB) void k_final(const float* __restrict__ ws,
                                              const int* __restrict__ imgw_p,
                                              float* __restrict__ out) {
    float v0 = 0.0f, v1 = 0.0f, v2 = 0.0f;
    for (int b = threadIdx.x; b < GRID; b += TB) {
        v0 += ws[0 * GRID + b];
        v1 += ws[1 * GRID + b];
        v2 += ws[2 * GRID + b];
    }
    for (int o = 32; o > 0; o >>= 1) {
        v0 += __shfl_down(v0, o, 64);
        v1 += __shfl_down(v1, o, 64);
        v2 += __shfl_down(v2, o, 64);
    }
    __shared__ float fm[3][4];
    const int lane = threadIdx.x & 63, wid = threadIdx.x >> 6;
    if (lane == 0) { fm[0][wid] = v0; fm[1][wid] = v1; fm[2][wid] = v2; }
    __syncthreads();
    if (threadIdx.x == 0) {
        const float s = (float)(*imgw_p) / 640.0f;
        out[0] = fm[0][0] + fm[0][1] + fm[0][2] + fm[0][3];
        out[1] = (fm[1][0] + fm[1][1] + fm[1][2] + fm[1][3]) * (L_OBJ * s * s);
        out[2] = fm[2][0] + fm[2][1] + fm[2][2] + fm[2][3];
    }
}

// ---------------- launch ----------------
extern "C" void kernel_launch(void* const* d_in, const int* in_sizes, int n_in,
                              void* d_out, int out_size, void* d_ws, size_t ws_size,
                              hipStream_t stream) {
    Scale ll{(const float*)d_in[0],  (const float*)d_in[1],  (const float*)d_in[2],
             (const int*)d_in[3],    (const int*)d_in[4],    (const int*)d_in[5],
             (const int*)d_in[6],    (const float*)d_in[7],  (const float*)d_in[8],
             (const int*)d_in[9],    G_LL};
    Scale ml{(const float*)d_in[10], (const float*)d_in[11], (const float*)d_in[12],
             (const int*)d_in[13],   (const int*)d_in[14],   (const int*)d_in[15],
             (const int*)d_in[16],   (const float*)d_in[17], (const float*)d_in[18],
             (const int*)d_in[19],   G_ML};
    Scale hl{(const float*)d_in[20], (const float*)d_in[21], (const float*)d_in[22],
             (const int*)d_in[23],   (const int*)d_in[24],   (const int*)d_in[25],
             (const int*)d_in[26],   (const float*)d_in[27], (const float*)d_in[28],
             (const int*)d_in[29],   G_HL};
    const int* imgw = (const int*)d_in[30];

    float* out = (float*)d_out;
    float* ws  = (float*)d_ws;   // 3*GRID floats = 11.2 KB, all written before read

    k_main<<<GRID, TB, 0, stream>>>(ll, ml, hl, ws);
    k_final<<<1, TB, 0, stream>>>(ws, imgw, out);
}